// Round 6
// baseline (267.856 us; speedup 1.0000x reference)
//
#include <hip/hip_runtime.h>
#include <hip/hip_fp16.h>
#include <math.h>

constexpr int kNodes = 50000;
constexpr int kEdges = 600000;
constexpr int kF     = 128;
constexpr int kNPB   = 64;        // nodes per block in gemm phase (4 waves x 16)
constexpr int kCap   = 48;        // fixed bucket capacity; P(deg>=48) ~ 3e-15/node

// R6 scan-fill geometry: 128 dst-ranges x 2 blocks (fwd/bwd edge halves).
constexpr int kRanges   = 128;
constexpr int kRangeSz  = (kNodes + kRanges - 1) / kRanges;   // 391
constexpr int kFillBlks = 2 * kRanges;                        // 256 (1 per CU)
constexpr int kHalfE    = kEdges / 2;                         // 300000
constexpr int kScanI4   = kHalfE / 4;                         // 75000 int4 per half
constexpr int kScanIters = kScanI4 / 256;                     // 292
constexpr int kScanRem   = kScanI4 - kScanIters * 256;        // 248

constexpr int kGemmB = (kNodes + kNPB - 1) / kNPB;            // 782
constexpr int kTotB  = kFillBlks + kGemmB;                    // 1038

// workspace layout (bytes)
constexpr size_t kOffWt     = 0;                                       // 32 KB Wfrag (64 KB region)
constexpr size_t kOffCur2   = 65536;                                   // int2 per node (df,db) = 400 KB
constexpr size_t kOffBucket = kOffCur2 + (size_t)kNodes * 8;           // ushort bucket, 4.8 MB
constexpr size_t kOffGpk    = kOffBucket + (size_t)kNodes * kCap * 2;  // 16B-aligned (5265536)
constexpr size_t kWsNeeded  = kOffGpk + (size_t)kNodes * kF * 2;       // ~17.9 MiB

typedef _Float16 f16x8 __attribute__((ext_vector_type(8)));
typedef float    f32x4 __attribute__((ext_vector_type(4)));

static __device__ __forceinline__ unsigned int packh2(float a, float b) {
    __half2 h = __floats2half2_rn(a, b);
    return *reinterpret_cast<unsigned int*>(&h);
}

// ---------------------------------------------------------------------------
// Kernel 0: pack W into MFMA A-fragment order as f16. (R6: cursor zeroing
// dropped — the scan-fill writes every node's counters unconditionally.)
// Fragment map for mfma_f32_16x16x32_f16, A-operand = W tile (16 outs x 32 k):
//   lane l, elem e -> row o_local = l&15, k_local = (l>>4)*8 + e
// Linear layout: Wf[(((nt*4)+ks)*64 + l)*8 + e], nt = o/16, ks = k/32.
__global__ __launch_bounds__(256) void prep0(const float* __restrict__ W,
                                             _Float16* __restrict__ Wf) {
    int gid = blockIdx.x * 256 + threadIdx.x;    // grid covers 16384
    if (gid < kF * kF) {
        int e  = gid & 7;
        int l  = (gid >> 3) & 63;
        int ks = (gid >> 9) & 3;
        int nt = gid >> 11;                      // 0..7
        int o  = nt * 16 + (l & 15);
        int k  = ks * 32 + ((l >> 4) & 3) * 8 + e;
        Wf[gid] = (_Float16)W[o * kF + k];
    }
}

// prep for the vestigial fallback path: fp32 W transpose
__global__ __launch_bounds__(256) void prep0_fb(const float* __restrict__ W,
                                                float* __restrict__ Wt) {
    int gid = blockIdx.x * 256 + threadIdx.x;
    if (gid < kF * kF) {
        int k = gid >> 7;
        int o = gid & (kF - 1);
        Wt[gid] = W[o * kF + k];
    }
}

// ---------------------------------------------------------------------------
// Kernel 1 (R6): fused scan-fill + MFMA gemm.
//
// FILL (blocks [0,256)): the ~35us global-atomic wall (flat across R0-R5
// against concurrency/padding/ordering) is bypassed entirely. Block pair
// (2r, 2r+1) owns dst-range [r*391,(r+1)*391): block 2r scans edge half
// [0,300k) filling bucket slots 0-upward, block 2r+1 scans [300k,600k)
// filling 47-downward. Slot counters are LDS (per-CU atomics, ~free);
// disjointness of the two writers follows from deg<=48 (same 3e-15
// assumption as before; byte-disjoint stores to shared lines from
// different XCDs are already exercised by R0-R5's slot-scattered stores).
// dst reads are fully coalesced int4, unroll-4 for load MLP; src is read
// scattered only for in-range hits (~1.6% of lanes). Final (df,db) counts
// written once per node — ZERO global atomics.
// Fill blocks go FIRST: 256 long-lived blocks spread 1/CU, gemm backfills.
// (Not R1's failure mode: no atomic churn, no short-block thrash.)
//
// GEMM (blocks [256,1038)): byte-identical to R5's restructure — all 8
// F-loads upfront, W fragments double-buffered across ks, split-precision
// F (hi+lo f16, chained MFMAs), no LDS, __launch_bounds__(256,3).
__global__ __launch_bounds__(256, 3) void gemm_fill(const float* __restrict__ F,
                                                    const _Float16* __restrict__ Wf,
                                                    const int* __restrict__ src,
                                                    const int* __restrict__ dst,
                                                    int* __restrict__ cur2,
                                                    unsigned short* __restrict__ bucket,
                                                    uint2* __restrict__ Gpk2) {
    __shared__ int curs[kRangeSz];   // 1.6 KB (fill blocks only)

    const int t = threadIdx.x;
    const int b = blockIdx.x;

    if (b < kFillBlks) {
        // ---- scan-fill phase ----
        const int rng  = b >> 1;          // 0..127
        const int dir  = b & 1;           // 0 = fwd (slots 0..), 1 = bwd (slots 47..)
        const int d0   = rng * kRangeSz;
        const int rlen = min(kRangeSz, kNodes - d0);

        for (int i = t; i < kRangeSz; i += 256) curs[i] = 0;
        __syncthreads();

        const int4* dv4 = reinterpret_cast<const int4*>(dst + dir * kHalfE);
        const int*  sv  = src + dir * kHalfE;

        auto body = [&](int i4) {
            int4 d4 = dv4[i4];
            int dd[4] = {d4.x, d4.y, d4.z, d4.w};
#pragma unroll
            for (int j = 0; j < 4; ++j) {
                unsigned r = (unsigned)(dd[j] - d0);
                if (r < (unsigned)rlen) {
                    int p = atomicAdd(&curs[r], 1);            // LDS atomic
                    unsigned short s = (unsigned short)sv[i4 * 4 + j];
                    if (p < kCap) {
                        int slot = dir ? (kCap - 1 - p) : p;
                        bucket[(size_t)dd[j] * kCap + slot] = s;
                    }
                }
            }
        };
#pragma unroll 4
        for (int k = 0; k < kScanIters; ++k) body(t + k * 256);
        if (t < kScanRem) body(t + kScanIters * 256);

        __syncthreads();
        for (int i = t; i < rlen; i += 256)
            cur2[(size_t)(d0 + i) * 2 + dir] = min(curs[i], kCap);
        return;
    }

    // ---- GEMM phase (per-wave independent 16-node strip) ----
    const int tile = b - kFillBlks;         // 0..781
    const int n0  = tile * kNPB;
    const int w   = t >> 6;                 // wave 0..3
    const int l   = t & 63;
    const int m0w = n0 + w * 16;
    if (m0w >= kNodes) return;              // last block: waves 1..3 fully OOB
    const int node  = m0w + (l & 15);       // B-operand col -> node
    const int nodeC = node < kNodes ? node : kNodes - 1;
    const int kbase = (l >> 4) * 8;         // this lane's K sub-chunk

    const f16x8* Wf8 = reinterpret_cast<const f16x8*>(Wf);
    const float* frow = F + (size_t)nodeC * kF + kbase;

    // 1) issue ALL F loads upfront (8 independent dwordx4)
    float4 f4[8];
#pragma unroll
    for (int ks = 0; ks < 4; ++ks) {
        f4[ks * 2 + 0] = *reinterpret_cast<const float4*>(frow + ks * 32);
        f4[ks * 2 + 1] = *reinterpret_cast<const float4*>(frow + ks * 32 + 4);
    }

    // 2) issue first W slice (ks=0) while F converts
    f16x8 wq[8];
#pragma unroll
    for (int nt = 0; nt < 8; ++nt) wq[nt] = Wf8[(nt * 4 + 0) * 64 + l];

    // 3) split F into hi/lo f16
    f16x8 bhi[4], blo[4];
#pragma unroll
    for (int ks = 0; ks < 4; ++ks) {
        const float* fv0 = reinterpret_cast<const float*>(&f4[ks * 2]);
#pragma unroll
        for (int i = 0; i < 8; ++i) {
            float v = fv0[i];
            _Float16 h = (_Float16)v;
            bhi[ks][i] = h;
            blo[ks][i] = (_Float16)(v - (float)h);
        }
    }

    f32x4 acc[8];
#pragma unroll
    for (int nt = 0; nt < 8; ++nt) acc[nt] = (f32x4){0.f, 0.f, 0.f, 0.f};

    // 4) ks loop: MFMA current W slice while prefetching the next
#pragma unroll
    for (int ks = 0; ks < 4; ++ks) {
        f16x8 wn[8];
        if (ks < 3) {
#pragma unroll
            for (int nt = 0; nt < 8; ++nt) wn[nt] = Wf8[(nt * 4 + ks + 1) * 64 + l];
        }
#pragma unroll
        for (int nt = 0; nt < 8; ++nt) {
            acc[nt] = __builtin_amdgcn_mfma_f32_16x16x32_f16(wq[nt], bhi[ks], acc[nt], 0, 0, 0);
            acc[nt] = __builtin_amdgcn_mfma_f32_16x16x32_f16(wq[nt], blo[ks], acc[nt], 0, 0, 0);
        }
        if (ks < 3) {
#pragma unroll
            for (int nt = 0; nt < 8; ++nt) wq[nt] = wn[nt];
        }
    }

    if (node < kNodes) {
        // acc[nt][j] = G[node][nt*16 + (l>>4)*4 + j]  (C/D: row=o_local, col=node_local)
#pragma unroll
        for (int nt = 0; nt < 8; ++nt) {
            uint2 p;
            p.x = packh2(acc[nt][0], acc[nt][1]);
            p.y = packh2(acc[nt][2], acc[nt][3]);
            Gpk2[(size_t)node * 32 + nt * 4 + (l >> 4)] = p;
        }
    }
}

// ---------------------------------------------------------------------------
// Kernel 2: out[n] = tanh(sum_{e: dst=n} G[src_e] + b). One wave per node,
// 4 edge-groups x 16 lanes; lane reads uint4 = 8 fp16 cols. Edge ids are
// prefetched once per wave and broadcast via __shfl.
// R6: bucket slots are now two runs — fwd [0,df) and bwd [48-db,48);
// lane->slot map handles the gap. deg = df+db.
// CORRECTNESS NOTE: the j-loop is WAVE-UNIFORM (iters = ceil(deg/4)) so the
// ds_bpermute behind __shfl always executes with all 64 lanes active —
// bpermute from an EXEC-inactive source lane returns undefined data. Only
// the load+accumulate is predicated.
__global__ __launch_bounds__(256) void gather_tanh(const uint4* __restrict__ Gpk4,
                                                   const unsigned short* __restrict__ bucket,
                                                   const int* __restrict__ cur2,
                                                   const float* __restrict__ bias,
                                                   float* __restrict__ out) {
    const int wave = (blockIdx.x * 256 + threadIdx.x) >> 6;
    const int lane = threadIdx.x & 63;
    if (wave >= kNodes) return;
    const int grp = lane >> 4;      // 0..3 : edge group
    const int sub = lane & 15;      // 0..15 : cols [sub*8, sub*8+8)

    int2 c2 = *reinterpret_cast<const int2*>(cur2 + (size_t)wave * 2);
    const int df  = min(c2.x, kCap);
    const int db  = min(c2.y, kCap);
    const int deg = min(df + db, kCap);
    const size_t base = (size_t)wave * kCap;

    // one load of all edge ids for this node (two contiguous runs, deg <= 48)
    const int slot = (lane < df) ? lane : (kCap - db + (lane - df));
    int eid = (lane < deg) ? (int)bucket[base + slot] : 0;

    float acc[8];
#pragma unroll
    for (int i = 0; i < 8; ++i) acc[i] = 0.0f;

    const int iters = (deg + 3) >> 2;   // uniform across the wave
#pragma unroll 2
    for (int i = 0; i < iters; ++i) {
        const int j = grp + 4 * i;
        const bool valid = (j < deg);
        int s = __shfl(eid, valid ? j : 0);   // full exec mask -> defined
        if (valid) {
            uint4 u = Gpk4[(size_t)s * 16 + sub];       // 16B -> 8 fp16
            const __half2* hp = reinterpret_cast<const __half2*>(&u);
#pragma unroll
            for (int q = 0; q < 4; ++q) {
                float2 f = __half22float2(hp[q]);
                acc[2 * q]     += f.x;
                acc[2 * q + 1] += f.y;
            }
        }
    }

#pragma unroll
    for (int i = 0; i < 8; ++i) {
        acc[i] += __shfl_xor(acc[i], 16);
        acc[i] += __shfl_xor(acc[i], 32);
    }

    if (grp == 0) {
        float4 b0 = *reinterpret_cast<const float4*>(bias + sub * 8);
        float4 b1 = *reinterpret_cast<const float4*>(bias + sub * 8 + 4);
        float4 r0, r1;
        r0.x = 1.0f - 2.0f / (__expf(2.0f * (acc[0] + b0.x)) + 1.0f);
        r0.y = 1.0f - 2.0f / (__expf(2.0f * (acc[1] + b0.y)) + 1.0f);
        r0.z = 1.0f - 2.0f / (__expf(2.0f * (acc[2] + b0.z)) + 1.0f);
        r0.w = 1.0f - 2.0f / (__expf(2.0f * (acc[3] + b0.w)) + 1.0f);
        r1.x = 1.0f - 2.0f / (__expf(2.0f * (acc[4] + b1.x)) + 1.0f);
        r1.y = 1.0f - 2.0f / (__expf(2.0f * (acc[5] + b1.y)) + 1.0f);
        r1.z = 1.0f - 2.0f / (__expf(2.0f * (acc[6] + b1.z)) + 1.0f);
        r1.w = 1.0f - 2.0f / (__expf(2.0f * (acc[7] + b1.w)) + 1.0f);
        float4* dstp = reinterpret_cast<float4*>(out + (size_t)wave * kF + sub * 8);
        dstp[0] = r0;
        dstp[1] = r1;
    }
}

// ---------------------------------------------------------------------------
// Fallback (vestigial — measured ws_size is 256 MiB): R1-style atomic scatter.
__global__ __launch_bounds__(256) void scatter_add(const float* __restrict__ feature,
                                                   const int* __restrict__ src,
                                                   const int* __restrict__ dst,
                                                   float* __restrict__ agg) {
    int gid = blockIdx.x * 256 + threadIdx.x;
    int e = gid >> 5;
    int c = (gid & 31) << 2;
    float4 v = *reinterpret_cast<const float4*>(feature + (size_t)src[e] * kF + c);
    float* p = agg + (size_t)dst[e] * kF + c;
    atomicAdd(p + 0, v.x);
    atomicAdd(p + 1, v.y);
    atomicAdd(p + 2, v.z);
    atomicAdd(p + 3, v.w);
}

__global__ __launch_bounds__(256, 4) void linear_tanh(float* __restrict__ inout,
                                                      const float* __restrict__ Wt,
                                                      const float* __restrict__ bias) {
    __shared__ float sAgg[kNPB * kF];
    __shared__ float sB[kF];
    const int t  = threadIdx.x;
    const int n0 = blockIdx.x * kNPB;
    if (t < kF) sB[t] = bias[t];
    const int rows = min(kNPB, kNodes - n0);
    for (int i = t * 4; i < rows * kF; i += 256 * 4)
        *reinterpret_cast<float4*>(&sAgg[i]) =
            *reinterpret_cast<const float4*>(inout + (size_t)n0 * kF + i);
    __syncthreads();
    const int tn = t >> 5, to = t & 31, nb = tn * 8;
    float acc[8][4];
#pragma unroll
    for (int n = 0; n < 8; ++n)
#pragma unroll
        for (int j = 0; j < 4; ++j) acc[n][j] = 0.0f;
    for (int k = 0; k < kF; k += 4) {
        float4 wt[4];
#pragma unroll
        for (int i = 0; i < 4; ++i)
            wt[i] = *reinterpret_cast<const float4*>(Wt + (k + i) * kF + to * 4);
#pragma unroll
        for (int n = 0; n < 8; ++n) {
            float4 av = *reinterpret_cast<const float4*>(&sAgg[(nb + n) * kF + k]);
#pragma unroll
            for (int j = 0; j < 4; ++j) {
                const float* w0 = reinterpret_cast<const float*>(&wt[0]);
                const float* w1 = reinterpret_cast<const float*>(&wt[1]);
                const float* w2 = reinterpret_cast<const float*>(&wt[2]);
                const float* w3 = reinterpret_cast<const float*>(&wt[3]);
                acc[n][j] += av.x * w0[j] + av.y * w1[j] + av.z * w2[j] + av.w * w3[j];
            }
        }
    }
#pragma unroll
    for (int n = 0; n < 8; ++n) {
        int node = n0 + nb + n;
        if (node < kNodes) {
            float4 r;
            r.x = 1.0f - 2.0f / (__expf(2.0f * (acc[n][0] + sB[to * 4 + 0])) + 1.0f);
            r.y = 1.0f - 2.0f / (__expf(2.0f * (acc[n][1] + sB[to * 4 + 1])) + 1.0f);
            r.z = 1.0f - 2.0f / (__expf(2.0f * (acc[n][2] + sB[to * 4 + 2])) + 1.0f);
            r.w = 1.0f - 2.0f / (__expf(2.0f * (acc[n][3] + sB[to * 4 + 3])) + 1.0f);
            *reinterpret_cast<float4*>(inout + (size_t)node * kF + to * 4) = r;
        }
    }
}

// ---------------------------------------------------------------------------
extern "C" void kernel_launch(void* const* d_in, const int* in_sizes, int n_in,
                              void* d_out, int out_size, void* d_ws, size_t ws_size,
                              hipStream_t stream) {
    const float* feature = (const float*)d_in[0];
    const float* W       = (const float*)d_in[1];
    const float* b       = (const float*)d_in[2];
    const int*   src     = (const int*)d_in[3];
    const int*   dst     = (const int*)d_in[4];
    float* out = (float*)d_out;

    char* ws = (char*)d_ws;
    _Float16* Wfrag  = (_Float16*)(ws + kOffWt);
    float*    Wt     = (float*)(ws + kOffWt);
    int*      cur2   = (int*)(ws + kOffCur2);
    unsigned short* bucket = (unsigned short*)(ws + kOffBucket);
    uint2*    Gpk2   = (uint2*)(ws + kOffGpk);

    if (ws_size >= kWsNeeded) {   // ws_size constant across calls -> graph-safe
        prep0<<<(kF * kF + 255) / 256, 256, 0, stream>>>(W, Wfrag);
        gemm_fill<<<kTotB, 256, 0, stream>>>(
            feature, Wfrag, src, dst, cur2, bucket, Gpk2);
        gather_tanh<<<(kNodes + 3) / 4, 256, 0, stream>>>(
            (const uint4*)Gpk2, bucket, cur2, b, out);
    } else {
        prep0_fb<<<(kF * kF + 255) / 256, 256, 0, stream>>>(W, Wt);
        hipMemsetAsync(out, 0, (size_t)kNodes * kF * sizeof(float), stream);
        scatter_add<<<(kEdges * 32) / 256, 256, 0, stream>>>(feature, src, dst, out);
        linear_tanh<<<(kNodes + kNPB - 1) / kNPB, 256, 0, stream>>>(out, Wt, b);
    }
}

// Round 7
// 187.675 us; speedup vs baseline: 1.4272x; 1.4272x over previous
//
#include <hip/hip_runtime.h>
#include <hip/hip_fp16.h>
#include <math.h>

constexpr int kNodes = 50000;
constexpr int kEdges = 600000;
constexpr int kF     = 128;
constexpr int kCap   = 48;        // fixed bucket capacity; P(deg>=48) ~ 3e-15/node

// R7 scan-fill geometry: 64 dst-ranges x 2 blocks (fwd/bwd edge halves),
// 1024 threads each (R6 failed at 256: 1 wave/SIMD = zero latency hiding).
constexpr int kRanges    = 64;
constexpr int kRangeSz   = (kNodes + kRanges - 1) / kRanges;  // 782
constexpr int kFillBlks  = 2 * kRanges;                       // 128 (half the CUs)
constexpr int kHalfE     = kEdges / 2;                        // 300000
constexpr int kScanI4    = kHalfE / 4;                        // 75000 int4 per half
constexpr int kFillT     = 1024;                              // 16 waves/block
constexpr int kScanIters = kScanI4 / kFillT;                  // 73
constexpr int kScanRem   = kScanI4 - kScanIters * kFillT;     // 248

// gemm geometry: 16 waves/block, one 16-node strip each -> 256 nodes/block
constexpr int kNPB   = 256;
constexpr int kGemmB = (kNodes + kNPB - 1) / kNPB;            // 196
constexpr int kTotB  = kFillBlks + kGemmB;                    // 324

// workspace layout (bytes)
constexpr size_t kOffWt     = 0;                                       // 32 KB Wfrag (64 KB region)
constexpr size_t kOffCur2   = 65536;                                   // int2 per node (df,db) = 400 KB
constexpr size_t kOffBucket = kOffCur2 + (size_t)kNodes * 8;           // ushort bucket, 4.8 MB
constexpr size_t kOffGpk    = kOffBucket + (size_t)kNodes * kCap * 2;  // 16B-aligned (5265536)
constexpr size_t kWsNeeded  = kOffGpk + (size_t)kNodes * kF * 2;       // ~17.9 MiB

typedef _Float16 f16x8 __attribute__((ext_vector_type(8)));
typedef float    f32x4 __attribute__((ext_vector_type(4)));

static __device__ __forceinline__ unsigned int packh2(float a, float b) {
    __half2 h = __floats2half2_rn(a, b);
    return *reinterpret_cast<unsigned int*>(&h);
}

// ---------------------------------------------------------------------------
// Kernel 0: pack W into MFMA A-fragment order as f16.
// Fragment map for mfma_f32_16x16x32_f16, A-operand = W tile (16 outs x 32 k):
//   lane l, elem e -> row o_local = l&15, k_local = (l>>4)*8 + e
// Linear layout: Wf[(((nt*4)+ks)*64 + l)*8 + e], nt = o/16, ks = k/32.
__global__ __launch_bounds__(256) void prep0(const float* __restrict__ W,
                                             _Float16* __restrict__ Wf) {
    int gid = blockIdx.x * 256 + threadIdx.x;    // grid covers 16384
    if (gid < kF * kF) {
        int e  = gid & 7;
        int l  = (gid >> 3) & 63;
        int ks = (gid >> 9) & 3;
        int nt = gid >> 11;                      // 0..7
        int o  = nt * 16 + (l & 15);
        int k  = ks * 32 + ((l >> 4) & 3) * 8 + e;
        Wf[gid] = (_Float16)W[o * kF + k];
    }
}

// prep for the vestigial fallback path: fp32 W transpose
__global__ __launch_bounds__(256) void prep0_fb(const float* __restrict__ W,
                                                float* __restrict__ Wt) {
    int gid = blockIdx.x * 256 + threadIdx.x;
    if (gid < kF * kF) {
        int k = gid >> 7;
        int o = gid & (kF - 1);
        Wt[gid] = W[o * kF + k];
    }
}

// ---------------------------------------------------------------------------
// Kernel 1 (R7): fused scan-fill + MFMA gemm, 1024 threads/block.
//
// FILL (blocks [0,128)): R6's algorithm (verified correct), re-geometried.
// Block pair (2r,2r+1) owns dst-range [r*782,(r+1)*782): block 2r scans
// edge half [0,300k) filling bucket slots 0-upward, 2r+1 scans [300k,600k)
// filling 47-downward. Slot counters in LDS (per-CU atomics), final (df,db)
// written once — ZERO global atomics. R6's failure was 256-thread blocks at
// 1/CU = 1 wave/SIMD: the sparse hit-body's latency (LDS atomic + scattered
// src load + scattered store) had nothing to hide under (13% occupancy, all
// pipes <8%). R7: 16 waves/block = 4 waves/SIMD, and only 128 blocks so the
// other half of the CUs run gemm concurrently. Redundant dst scan traffic
// halves (154 MB, L2-absorbed — R6's FETCH confirmed L2 absorbs this).
//
// GEMM (blocks [128,324)): R5's verified per-wave strip (all F-loads
// upfront, W double-buffered across ks, split-precision hi+lo f16 MFMA),
// re-tiled to 16 waves/block covering 256 nodes.
__global__ __launch_bounds__(1024, 4) void gemm_fill(const float* __restrict__ F,
                                                     const _Float16* __restrict__ Wf,
                                                     const int* __restrict__ src,
                                                     const int* __restrict__ dst,
                                                     int* __restrict__ cur2,
                                                     unsigned short* __restrict__ bucket,
                                                     uint2* __restrict__ Gpk2) {
    __shared__ int curs[kRangeSz];   // 3.1 KB (fill blocks only)

    const int t = threadIdx.x;
    const int b = blockIdx.x;

    if (b < kFillBlks) {
        // ---- scan-fill phase ----
        const int rng  = b >> 1;          // 0..63
        const int dir  = b & 1;           // 0 = fwd (slots 0..), 1 = bwd (slots 47..)
        const int d0   = rng * kRangeSz;
        const int rlen = min(kRangeSz, kNodes - d0);

        for (int i = t; i < kRangeSz; i += kFillT) curs[i] = 0;
        __syncthreads();

        const int4* dv4 = reinterpret_cast<const int4*>(dst + dir * kHalfE);
        const int*  sv  = src + dir * kHalfE;

        auto body = [&](int i4) {
            int4 d4 = dv4[i4];
            int dd[4] = {d4.x, d4.y, d4.z, d4.w};
#pragma unroll
            for (int j = 0; j < 4; ++j) {
                unsigned r = (unsigned)(dd[j] - d0);
                if (r < (unsigned)rlen) {
                    int p = atomicAdd(&curs[r], 1);            // LDS atomic
                    unsigned short s = (unsigned short)sv[i4 * 4 + j];
                    if (p < kCap) {
                        int slot = dir ? (kCap - 1 - p) : p;
                        bucket[(size_t)dd[j] * kCap + slot] = s;
                    }
                }
            }
        };
#pragma unroll 4
        for (int k = 0; k < kScanIters; ++k) body(t + k * kFillT);
        if (t < kScanRem) body(t + kScanIters * kFillT);

        __syncthreads();
        for (int i = t; i < rlen; i += kFillT)
            cur2[(size_t)(d0 + i) * 2 + dir] = min(curs[i], kCap);
        return;
    }

    // ---- GEMM phase (per-wave independent 16-node strip; 16 waves/block) ----
    const int tile = b - kFillBlks;         // 0..195
    const int n0  = tile * kNPB;
    const int w   = t >> 6;                 // wave 0..15
    const int l   = t & 63;
    const int m0w = n0 + w * 16;
    if (m0w >= kNodes) return;              // tail block: high waves fully OOB
    const int node  = m0w + (l & 15);       // B-operand col -> node
    const int nodeC = node < kNodes ? node : kNodes - 1;
    const int kbase = (l >> 4) * 8;         // this lane's K sub-chunk

    const f16x8* Wf8 = reinterpret_cast<const f16x8*>(Wf);
    const float* frow = F + (size_t)nodeC * kF + kbase;

    // 1) issue ALL F loads upfront (8 independent dwordx4)
    float4 f4[8];
#pragma unroll
    for (int ks = 0; ks < 4; ++ks) {
        f4[ks * 2 + 0] = *reinterpret_cast<const float4*>(frow + ks * 32);
        f4[ks * 2 + 1] = *reinterpret_cast<const float4*>(frow + ks * 32 + 4);
    }

    // 2) issue first W slice (ks=0) while F converts
    f16x8 wq[8];
#pragma unroll
    for (int nt = 0; nt < 8; ++nt) wq[nt] = Wf8[(nt * 4 + 0) * 64 + l];

    // 3) split F into hi/lo f16
    f16x8 bhi[4], blo[4];
#pragma unroll
    for (int ks = 0; ks < 4; ++ks) {
        const float* fv0 = reinterpret_cast<const float*>(&f4[ks * 2]);
#pragma unroll
        for (int i = 0; i < 8; ++i) {
            float v = fv0[i];
            _Float16 h = (_Float16)v;
            bhi[ks][i] = h;
            blo[ks][i] = (_Float16)(v - (float)h);
        }
    }

    f32x4 acc[8];
#pragma unroll
    for (int nt = 0; nt < 8; ++nt) acc[nt] = (f32x4){0.f, 0.f, 0.f, 0.f};

    // 4) ks loop: MFMA current W slice while prefetching the next
#pragma unroll
    for (int ks = 0; ks < 4; ++ks) {
        f16x8 wn[8];
        if (ks < 3) {
#pragma unroll
            for (int nt = 0; nt < 8; ++nt) wn[nt] = Wf8[(nt * 4 + ks + 1) * 64 + l];
        }
#pragma unroll
        for (int nt = 0; nt < 8; ++nt) {
            acc[nt] = __builtin_amdgcn_mfma_f32_16x16x32_f16(wq[nt], bhi[ks], acc[nt], 0, 0, 0);
            acc[nt] = __builtin_amdgcn_mfma_f32_16x16x32_f16(wq[nt], blo[ks], acc[nt], 0, 0, 0);
        }
        if (ks < 3) {
#pragma unroll
            for (int nt = 0; nt < 8; ++nt) wq[nt] = wn[nt];
        }
    }

    if (node < kNodes) {
        // acc[nt][j] = G[node][nt*16 + (l>>4)*4 + j]  (C/D: row=o_local, col=node_local)
#pragma unroll
        for (int nt = 0; nt < 8; ++nt) {
            uint2 p;
            p.x = packh2(acc[nt][0], acc[nt][1]);
            p.y = packh2(acc[nt][2], acc[nt][3]);
            Gpk2[(size_t)node * 32 + nt * 4 + (l >> 4)] = p;
        }
    }
}

// ---------------------------------------------------------------------------
// Kernel 2: out[n] = tanh(sum_{e: dst=n} G[src_e] + b). One wave per node,
// 4 edge-groups x 16 lanes; lane reads uint4 = 8 fp16 cols. Edge ids are
// prefetched once per wave and broadcast via __shfl.
// Bucket slots are two runs — fwd [0,df) and bwd [48-db,48); lane->slot map
// handles the gap. deg = df+db. (Verified in R6.)
// CORRECTNESS NOTE: the j-loop is WAVE-UNIFORM (iters = ceil(deg/4)) so the
// ds_bpermute behind __shfl always executes with all 64 lanes active —
// bpermute from an EXEC-inactive source lane returns undefined data. Only
// the load+accumulate is predicated.
__global__ __launch_bounds__(256) void gather_tanh(const uint4* __restrict__ Gpk4,
                                                   const unsigned short* __restrict__ bucket,
                                                   const int* __restrict__ cur2,
                                                   const float* __restrict__ bias,
                                                   float* __restrict__ out) {
    const int wave = (blockIdx.x * 256 + threadIdx.x) >> 6;
    const int lane = threadIdx.x & 63;
    if (wave >= kNodes) return;
    const int grp = lane >> 4;      // 0..3 : edge group
    const int sub = lane & 15;      // 0..15 : cols [sub*8, sub*8+8)

    int2 c2 = *reinterpret_cast<const int2*>(cur2 + (size_t)wave * 2);
    const int df  = min(c2.x, kCap);
    const int db  = min(c2.y, kCap);
    const int deg = min(df + db, kCap);
    const size_t base = (size_t)wave * kCap;

    // one load of all edge ids for this node (two contiguous runs, deg <= 48)
    const int slot = (lane < df) ? lane : (kCap - db + (lane - df));
    int eid = (lane < deg) ? (int)bucket[base + slot] : 0;

    float acc[8];
#pragma unroll
    for (int i = 0; i < 8; ++i) acc[i] = 0.0f;

    const int iters = (deg + 3) >> 2;   // uniform across the wave
#pragma unroll 2
    for (int i = 0; i < iters; ++i) {
        const int j = grp + 4 * i;
        const bool valid = (j < deg);
        int s = __shfl(eid, valid ? j : 0);   // full exec mask -> defined
        if (valid) {
            uint4 u = Gpk4[(size_t)s * 16 + sub];       // 16B -> 8 fp16
            const __half2* hp = reinterpret_cast<const __half2*>(&u);
#pragma unroll
            for (int q = 0; q < 4; ++q) {
                float2 f = __half22float2(hp[q]);
                acc[2 * q]     += f.x;
                acc[2 * q + 1] += f.y;
            }
        }
    }

#pragma unroll
    for (int i = 0; i < 8; ++i) {
        acc[i] += __shfl_xor(acc[i], 16);
        acc[i] += __shfl_xor(acc[i], 32);
    }

    if (grp == 0) {
        float4 b0 = *reinterpret_cast<const float4*>(bias + sub * 8);
        float4 b1 = *reinterpret_cast<const float4*>(bias + sub * 8 + 4);
        float4 r0, r1;
        r0.x = 1.0f - 2.0f / (__expf(2.0f * (acc[0] + b0.x)) + 1.0f);
        r0.y = 1.0f - 2.0f / (__expf(2.0f * (acc[1] + b0.y)) + 1.0f);
        r0.z = 1.0f - 2.0f / (__expf(2.0f * (acc[2] + b0.z)) + 1.0f);
        r0.w = 1.0f - 2.0f / (__expf(2.0f * (acc[3] + b0.w)) + 1.0f);
        r1.x = 1.0f - 2.0f / (__expf(2.0f * (acc[4] + b1.x)) + 1.0f);
        r1.y = 1.0f - 2.0f / (__expf(2.0f * (acc[5] + b1.y)) + 1.0f);
        r1.z = 1.0f - 2.0f / (__expf(2.0f * (acc[6] + b1.z)) + 1.0f);
        r1.w = 1.0f - 2.0f / (__expf(2.0f * (acc[7] + b1.w)) + 1.0f);
        float4* dstp = reinterpret_cast<float4*>(out + (size_t)wave * kF + sub * 8);
        dstp[0] = r0;
        dstp[1] = r1;
    }
}

// ---------------------------------------------------------------------------
// Fallback (vestigial — measured ws_size is 256 MiB): R1-style atomic scatter.
__global__ __launch_bounds__(256) void scatter_add(const float* __restrict__ feature,
                                                   const int* __restrict__ src,
                                                   const int* __restrict__ dst,
                                                   float* __restrict__ agg) {
    int gid = blockIdx.x * 256 + threadIdx.x;
    int e = gid >> 5;
    int c = (gid & 31) << 2;
    float4 v = *reinterpret_cast<const float4*>(feature + (size_t)src[e] * kF + c);
    float* p = agg + (size_t)dst[e] * kF + c;
    atomicAdd(p + 0, v.x);
    atomicAdd(p + 1, v.y);
    atomicAdd(p + 2, v.z);
    atomicAdd(p + 3, v.w);
}

__global__ __launch_bounds__(256, 4) void linear_tanh(float* __restrict__ inout,
                                                      const float* __restrict__ Wt,
                                                      const float* __restrict__ bias) {
    __shared__ float sAgg[64 * kF];
    __shared__ float sB[kF];
    const int t  = threadIdx.x;
    const int n0 = blockIdx.x * 64;
    if (t < kF) sB[t] = bias[t];
    const int rows = min(64, kNodes - n0);
    for (int i = t * 4; i < rows * kF; i += 256 * 4)
        *reinterpret_cast<float4*>(&sAgg[i]) =
            *reinterpret_cast<const float4*>(inout + (size_t)n0 * kF + i);
    __syncthreads();
    const int tn = t >> 5, to = t & 31, nb = tn * 8;
    float acc[8][4];
#pragma unroll
    for (int n = 0; n < 8; ++n)
#pragma unroll
        for (int j = 0; j < 4; ++j) acc[n][j] = 0.0f;
    for (int k = 0; k < kF; k += 4) {
        float4 wt[4];
#pragma unroll
        for (int i = 0; i < 4; ++i)
            wt[i] = *reinterpret_cast<const float4*>(Wt + (k + i) * kF + to * 4);
#pragma unroll
        for (int n = 0; n < 8; ++n) {
            float4 av = *reinterpret_cast<const float4*>(&sAgg[(nb + n) * kF + k]);
#pragma unroll
            for (int j = 0; j < 4; ++j) {
                const float* w0 = reinterpret_cast<const float*>(&wt[0]);
                const float* w1 = reinterpret_cast<const float*>(&wt[1]);
                const float* w2 = reinterpret_cast<const float*>(&wt[2]);
                const float* w3 = reinterpret_cast<const float*>(&wt[3]);
                acc[n][j] += av.x * w0[j] + av.y * w1[j] + av.z * w2[j] + av.w * w3[j];
            }
        }
    }
#pragma unroll
    for (int n = 0; n < 8; ++n) {
        int node = n0 + nb + n;
        if (node < kNodes) {
            float4 r;
            r.x = 1.0f - 2.0f / (__expf(2.0f * (acc[n][0] + sB[to * 4 + 0])) + 1.0f);
            r.y = 1.0f - 2.0f / (__expf(2.0f * (acc[n][1] + sB[to * 4 + 1])) + 1.0f);
            r.z = 1.0f - 2.0f / (__expf(2.0f * (acc[n][2] + sB[to * 4 + 2])) + 1.0f);
            r.w = 1.0f - 2.0f / (__expf(2.0f * (acc[n][3] + sB[to * 4 + 3])) + 1.0f);
            *reinterpret_cast<float4*>(inout + (size_t)node * kF + to * 4) = r;
        }
    }
}

// ---------------------------------------------------------------------------
extern "C" void kernel_launch(void* const* d_in, const int* in_sizes, int n_in,
                              void* d_out, int out_size, void* d_ws, size_t ws_size,
                              hipStream_t stream) {
    const float* feature = (const float*)d_in[0];
    const float* W       = (const float*)d_in[1];
    const float* b       = (const float*)d_in[2];
    const int*   src     = (const int*)d_in[3];
    const int*   dst     = (const int*)d_in[4];
    float* out = (float*)d_out;

    char* ws = (char*)d_ws;
    _Float16* Wfrag  = (_Float16*)(ws + kOffWt);
    float*    Wt     = (float*)(ws + kOffWt);
    int*      cur2   = (int*)(ws + kOffCur2);
    unsigned short* bucket = (unsigned short*)(ws + kOffBucket);
    uint2*    Gpk2   = (uint2*)(ws + kOffGpk);

    if (ws_size >= kWsNeeded) {   // ws_size constant across calls -> graph-safe
        prep0<<<(kF * kF + 255) / 256, 256, 0, stream>>>(W, Wfrag);
        gemm_fill<<<kTotB, kFillT, 0, stream>>>(
            feature, Wfrag, src, dst, cur2, bucket, Gpk2);
        gather_tanh<<<(kNodes + 3) / 4, 256, 0, stream>>>(
            (const uint4*)Gpk2, bucket, cur2, b, out);
    } else {
        prep0_fb<<<(kF * kF + 255) / 256, 256, 0, stream>>>(W, Wt);
        hipMemsetAsync(out, 0, (size_t)kNodes * kF * sizeof(float), stream);
        scatter_add<<<(kEdges * 32) / 256, 256, 0, stream>>>(feature, src, dst, out);
        linear_tanh<<<(kNodes + 63) / 64, 256, 0, stream>>>(out, Wt, b);
    }
}

// Round 8
// 138.622 us; speedup vs baseline: 1.9323x; 1.3539x over previous
//
#include <hip/hip_runtime.h>
#include <hip/hip_fp16.h>
#include <math.h>

constexpr int kNodes = 50000;
constexpr int kEdges = 600000;
constexpr int kF     = 128;
constexpr int kCap   = 48;        // bucket capacity/node; P(deg>=48) ~ 3e-15/node

// R8 two-phase bucket build geometry
constexpr int kRS      = 256;                      // nodes per range (loc = d & 255)
constexpr int kRanges  = (kNodes + kRS - 1) / kRS; // 196 (r = d >> 8)
constexpr int kABlk    = 586;                      // bin blocks, 1024 edges each
constexpr int kSegCap  = 24;                       // per-(block,range) segment cap
                                                   // lambda=5.22 -> P(any overflow) ~8e-4, graph fixed
constexpr int kI4      = kEdges / 4;               // 150000 int4s (exact)

// gemm geometry (R5, verified): 4 waves/block, 16-node strip per wave
constexpr int kNPB    = 64;
constexpr int kGemmB  = (kNodes + kNPB - 1) / kNPB;  // 782
constexpr int kFusedB = kRanges + kGemmB;            // 978

// workspace layout (bytes)
constexpr size_t kOffWt     = 0;                                        // 32 KB Wfrag
constexpr size_t kOffCnt    = 65536;                                    // cntA[r][b] 196x586 int = 459424
constexpr size_t kOffPool   = kOffCnt + (size_t)kRanges * kABlk * 4;    // 524960 (16B-aligned)
constexpr size_t kOffBucket = kOffPool + (size_t)kABlk * kRanges * kSegCap * 4;  // 11.55 MB
constexpr size_t kOffDeg    = kOffBucket + (size_t)kNodes * kCap * 2;   // +4.8 MB
constexpr size_t kOffGpk    = kOffDeg + (size_t)kNodes * 4;             // 16B-aligned (16551136)
constexpr size_t kWsNeeded  = kOffGpk + (size_t)kNodes * kF * 2;        // ~28 MiB

typedef _Float16 f16x8 __attribute__((ext_vector_type(8)));
typedef float    f32x4 __attribute__((ext_vector_type(4)));

static __device__ __forceinline__ unsigned int packh2(float a, float b) {
    __half2 h = __floats2half2_rn(a, b);
    return *reinterpret_cast<unsigned int*>(&h);
}

// ---------------------------------------------------------------------------
// Kernel 0: pack W into MFMA A-fragment order as f16.
// Fragment map for mfma_f32_16x16x32_f16, A-operand = W tile (16 outs x 32 k):
//   lane l, elem e -> row o_local = l&15, k_local = (l>>4)*8 + e
// Linear layout: Wf[(((nt*4)+ks)*64 + l)*8 + e], nt = o/16, ks = k/32.
__global__ __launch_bounds__(256) void prep0(const float* __restrict__ W,
                                             _Float16* __restrict__ Wf) {
    int gid = blockIdx.x * 256 + threadIdx.x;    // grid covers 16384
    if (gid < kF * kF) {
        int e  = gid & 7;
        int l  = (gid >> 3) & 63;
        int ks = (gid >> 9) & 3;
        int nt = gid >> 11;                      // 0..7
        int o  = nt * 16 + (l & 15);
        int k  = ks * 32 + ((l >> 4) & 3) * 8 + e;
        Wf[gid] = (_Float16)W[o * kF + k];
    }
}

// prep for the vestigial fallback path: fp32 W transpose
__global__ __launch_bounds__(256) void prep0_fb(const float* __restrict__ W,
                                                float* __restrict__ Wt) {
    int gid = blockIdx.x * 256 + threadIdx.x;
    if (gid < kF * kF) {
        int k = gid >> 7;
        int o = gid & (kF - 1);
        Wt[gid] = W[o * kF + k];
    }
}

// ---------------------------------------------------------------------------
// Kernel A (R8): bin edges by dst-range into fixed-capacity pool segments.
// Block b owns edges [b*1024,(b+1)*1024): coalesced int4 reads, each edge
// read ONCE (kills R6/R7's 128x redundant scan). LDS counters (196 ints)
// give the within-segment slot — NO global atomics (kills R0-R5's ~35us
// device-atomic wall). Entry = (loc<<16)|src (loc = dst&255 < 256, src <
// 50000 < 2^16). Pool layout [b][r]: block writes land in a contiguous
// 18.8KB window (L2 write-combining); cntA layout [r][b] so phase B reads
// its 586 counts contiguously.
__global__ __launch_bounds__(256) void binA(const int* __restrict__ src,
                                            const int* __restrict__ dst,
                                            unsigned int* __restrict__ pool,
                                            int* __restrict__ cntA) {
    __shared__ int c[kRanges];
    const int t = threadIdx.x;
    const int b = blockIdx.x;
    if (t < kRanges) c[t] = 0;
    __syncthreads();

    const int i4 = b * 256 + t;
    if (i4 < kI4) {
        int4 d4 = *reinterpret_cast<const int4*>(dst + i4 * 4);
        int4 s4 = *reinterpret_cast<const int4*>(src + i4 * 4);
        int dd[4] = {d4.x, d4.y, d4.z, d4.w};
        int ss[4] = {s4.x, s4.y, s4.z, s4.w};
#pragma unroll
        for (int j = 0; j < 4; ++j) {
            int r   = dd[j] >> 8;            // 0..195
            int loc = dd[j] & (kRS - 1);     // 0..255
            int p   = atomicAdd(&c[r], 1);   // LDS atomic
            if (p < kSegCap)                 // never triggers (see kSegCap note)
                pool[((size_t)b * kRanges + r) * kSegCap + p] =
                    ((unsigned)loc << 16) | (unsigned)ss[j];
        }
    }
    __syncthreads();
    if (t < kRanges) cntA[(size_t)t * kABlk + b] = min(c[t], kSegCap);
}

// ---------------------------------------------------------------------------
// Kernel 1 (R8): fused place + MFMA gemm.
//
// PLACE (blocks [0,196)): block r owns nodes [r*256, r*256+256). Loads its
// 586 segment counts (contiguous) into LDS, reads segments as 16B uint4
// (segments are 96B-aligned; overread stays inside the 24-entry cap), and
// places entries via LDS cursor atomics into the single-run ushort bucket.
// 100% hit rate — no wasted scan, no global atomics. Writes deg[] for every
// owned node (covers all 50000; no zeroing kernel needed).
//
// GEMM (blocks [196,978)): R5's verified per-wave 16-node strip — all 8
// F-loads upfront, W fragments double-buffered across ks, split-precision
// F (hi+lo f16, chained MFMAs), no LDS use, 3 blocks/CU.
__global__ __launch_bounds__(256, 3) void place_gemm(const float* __restrict__ F,
                                                     const _Float16* __restrict__ Wf,
                                                     const unsigned int* __restrict__ pool,
                                                     const int* __restrict__ cntA,
                                                     unsigned short* __restrict__ bucket,
                                                     int* __restrict__ deg,
                                                     uint2* __restrict__ Gpk2) {
    __shared__ int curs[kRS];
    __shared__ int scnt[kABlk];

    const int t = threadIdx.x;
    const int b = blockIdx.x;

    if (b < kRanges) {
        // ---- place phase ----
        const int r = b;
        curs[t] = 0;
        for (int i = t; i < kABlk; i += 256) scnt[i] = cntA[(size_t)r * kABlk + i];
        __syncthreads();

        for (int b2 = t; b2 < kABlk; b2 += 256) {
            const int cnt = scnt[b2];
            const unsigned int* segp = pool + ((size_t)b2 * kRanges + r) * kSegCap;
            for (int i = 0; i < cnt; i += 4) {
                uint4 u4 = *reinterpret_cast<const uint4*>(segp + i);  // 96B-aligned seg
                unsigned uu[4] = {u4.x, u4.y, u4.z, u4.w};
#pragma unroll
                for (int j = 0; j < 4; ++j) {
                    if (i + j < cnt) {
                        int loc = (int)(uu[j] >> 16);
                        int s   = (int)(uu[j] & 0xFFFFu);
                        int q   = atomicAdd(&curs[loc], 1);   // LDS atomic
                        if (q < kCap)
                            bucket[(size_t)(r * kRS + loc) * kCap + q] = (unsigned short)s;
                    }
                }
            }
        }
        __syncthreads();
        const int node = r * kRS + t;
        if (node < kNodes) deg[node] = min(curs[t], kCap);
        return;
    }

    // ---- GEMM phase (per-wave independent 16-node strip) ----
    const int tile = b - kRanges;           // 0..781
    const int n0  = tile * kNPB;
    const int w   = t >> 6;                 // wave 0..3
    const int l   = t & 63;
    const int m0w = n0 + w * 16;
    if (m0w >= kNodes) return;              // last block: waves 1..3 fully OOB
    const int node  = m0w + (l & 15);       // B-operand col -> node
    const int nodeC = node < kNodes ? node : kNodes - 1;
    const int kbase = (l >> 4) * 8;         // this lane's K sub-chunk

    const f16x8* Wf8 = reinterpret_cast<const f16x8*>(Wf);
    const float* frow = F + (size_t)nodeC * kF + kbase;

    // 1) issue ALL F loads upfront (8 independent dwordx4)
    float4 f4[8];
#pragma unroll
    for (int ks = 0; ks < 4; ++ks) {
        f4[ks * 2 + 0] = *reinterpret_cast<const float4*>(frow + ks * 32);
        f4[ks * 2 + 1] = *reinterpret_cast<const float4*>(frow + ks * 32 + 4);
    }

    // 2) issue first W slice (ks=0) while F converts
    f16x8 wq[8];
#pragma unroll
    for (int nt = 0; nt < 8; ++nt) wq[nt] = Wf8[(nt * 4 + 0) * 64 + l];

    // 3) split F into hi/lo f16
    f16x8 bhi[4], blo[4];
#pragma unroll
    for (int ks = 0; ks < 4; ++ks) {
        const float* fv0 = reinterpret_cast<const float*>(&f4[ks * 2]);
#pragma unroll
        for (int i = 0; i < 8; ++i) {
            float v = fv0[i];
            _Float16 h = (_Float16)v;
            bhi[ks][i] = h;
            blo[ks][i] = (_Float16)(v - (float)h);
        }
    }

    f32x4 acc[8];
#pragma unroll
    for (int nt = 0; nt < 8; ++nt) acc[nt] = (f32x4){0.f, 0.f, 0.f, 0.f};

    // 4) ks loop: MFMA current W slice while prefetching the next
#pragma unroll
    for (int ks = 0; ks < 4; ++ks) {
        f16x8 wn[8];
        if (ks < 3) {
#pragma unroll
            for (int nt = 0; nt < 8; ++nt) wn[nt] = Wf8[(nt * 4 + ks + 1) * 64 + l];
        }
#pragma unroll
        for (int nt = 0; nt < 8; ++nt) {
            acc[nt] = __builtin_amdgcn_mfma_f32_16x16x32_f16(wq[nt], bhi[ks], acc[nt], 0, 0, 0);
            acc[nt] = __builtin_amdgcn_mfma_f32_16x16x32_f16(wq[nt], blo[ks], acc[nt], 0, 0, 0);
        }
        if (ks < 3) {
#pragma unroll
            for (int nt = 0; nt < 8; ++nt) wq[nt] = wn[nt];
        }
    }

    if (node < kNodes) {
        // acc[nt][j] = G[node][nt*16 + (l>>4)*4 + j]  (C/D: row=o_local, col=node_local)
#pragma unroll
        for (int nt = 0; nt < 8; ++nt) {
            uint2 p;
            p.x = packh2(acc[nt][0], acc[nt][1]);
            p.y = packh2(acc[nt][2], acc[nt][3]);
            Gpk2[(size_t)node * 32 + nt * 4 + (l >> 4)] = p;
        }
    }
}

// ---------------------------------------------------------------------------
// Kernel 2: out[n] = tanh(sum_{e: dst=n} G[src_e] + b). One wave per node,
// 4 edge-groups x 16 lanes; lane reads uint4 = 8 fp16 cols. Edge ids are
// prefetched once per wave and broadcast via __shfl. Single-run bucket
// (restored pre-R6 form; deg from dense deg[] array).
// CORRECTNESS NOTE: the j-loop is WAVE-UNIFORM (iters = ceil(deg/4)) so the
// ds_bpermute behind __shfl always executes with all 64 lanes active —
// bpermute from an EXEC-inactive source lane returns undefined data. Only
// the load+accumulate is predicated.
__global__ __launch_bounds__(256) void gather_tanh(const uint4* __restrict__ Gpk4,
                                                   const unsigned short* __restrict__ bucket,
                                                   const int* __restrict__ deg_arr,
                                                   const float* __restrict__ bias,
                                                   float* __restrict__ out) {
    const int wave = (blockIdx.x * 256 + threadIdx.x) >> 6;
    const int lane = threadIdx.x & 63;
    if (wave >= kNodes) return;
    const int grp = lane >> 4;      // 0..3 : edge group
    const int sub = lane & 15;      // 0..15 : cols [sub*8, sub*8+8)

    const int deg = min(deg_arr[wave], kCap);
    const size_t base = (size_t)wave * kCap;

    // one coalesced load of all edge ids for this node (deg <= 48 < 64)
    int eid = (lane < deg) ? (int)bucket[base + lane] : 0;

    float acc[8];
#pragma unroll
    for (int i = 0; i < 8; ++i) acc[i] = 0.0f;

    const int iters = (deg + 3) >> 2;   // uniform across the wave
#pragma unroll 2
    for (int i = 0; i < iters; ++i) {
        const int j = grp + 4 * i;
        const bool valid = (j < deg);
        int s = __shfl(eid, valid ? j : 0);   // full exec mask -> defined
        if (valid) {
            uint4 u = Gpk4[(size_t)s * 16 + sub];       // 16B -> 8 fp16
            const __half2* hp = reinterpret_cast<const __half2*>(&u);
#pragma unroll
            for (int q = 0; q < 4; ++q) {
                float2 f = __half22float2(hp[q]);
                acc[2 * q]     += f.x;
                acc[2 * q + 1] += f.y;
            }
        }
    }

#pragma unroll
    for (int i = 0; i < 8; ++i) {
        acc[i] += __shfl_xor(acc[i], 16);
        acc[i] += __shfl_xor(acc[i], 32);
    }

    if (grp == 0) {
        float4 b0 = *reinterpret_cast<const float4*>(bias + sub * 8);
        float4 b1 = *reinterpret_cast<const float4*>(bias + sub * 8 + 4);
        float4 r0, r1;
        r0.x = 1.0f - 2.0f / (__expf(2.0f * (acc[0] + b0.x)) + 1.0f);
        r0.y = 1.0f - 2.0f / (__expf(2.0f * (acc[1] + b0.y)) + 1.0f);
        r0.z = 1.0f - 2.0f / (__expf(2.0f * (acc[2] + b0.z)) + 1.0f);
        r0.w = 1.0f - 2.0f / (__expf(2.0f * (acc[3] + b0.w)) + 1.0f);
        r1.x = 1.0f - 2.0f / (__expf(2.0f * (acc[4] + b1.x)) + 1.0f);
        r1.y = 1.0f - 2.0f / (__expf(2.0f * (acc[5] + b1.y)) + 1.0f);
        r1.z = 1.0f - 2.0f / (__expf(2.0f * (acc[6] + b1.z)) + 1.0f);
        r1.w = 1.0f - 2.0f / (__expf(2.0f * (acc[7] + b1.w)) + 1.0f);
        float4* dstp = reinterpret_cast<float4*>(out + (size_t)wave * kF + sub * 8);
        dstp[0] = r0;
        dstp[1] = r1;
    }
}

// ---------------------------------------------------------------------------
// Fallback (vestigial — measured ws_size is 256 MiB): R1-style atomic scatter.
__global__ __launch_bounds__(256) void scatter_add(const float* __restrict__ feature,
                                                   const int* __restrict__ src,
                                                   const int* __restrict__ dst,
                                                   float* __restrict__ agg) {
    int gid = blockIdx.x * 256 + threadIdx.x;
    int e = gid >> 5;
    int c = (gid & 31) << 2;
    float4 v = *reinterpret_cast<const float4*>(feature + (size_t)src[e] * kF + c);
    float* p = agg + (size_t)dst[e] * kF + c;
    atomicAdd(p + 0, v.x);
    atomicAdd(p + 1, v.y);
    atomicAdd(p + 2, v.z);
    atomicAdd(p + 3, v.w);
}

__global__ __launch_bounds__(256, 4) void linear_tanh(float* __restrict__ inout,
                                                      const float* __restrict__ Wt,
                                                      const float* __restrict__ bias) {
    __shared__ float sAgg[64 * kF];
    __shared__ float sB[kF];
    const int t  = threadIdx.x;
    const int n0 = blockIdx.x * 64;
    if (t < kF) sB[t] = bias[t];
    const int rows = min(64, kNodes - n0);
    for (int i = t * 4; i < rows * kF; i += 256 * 4)
        *reinterpret_cast<float4*>(&sAgg[i]) =
            *reinterpret_cast<const float4*>(inout + (size_t)n0 * kF + i);
    __syncthreads();
    const int tn = t >> 5, to = t & 31, nb = tn * 8;
    float acc[8][4];
#pragma unroll
    for (int n = 0; n < 8; ++n)
#pragma unroll
        for (int j = 0; j < 4; ++j) acc[n][j] = 0.0f;
    for (int k = 0; k < kF; k += 4) {
        float4 wt[4];
#pragma unroll
        for (int i = 0; i < 4; ++i)
            wt[i] = *reinterpret_cast<const float4*>(Wt + (k + i) * kF + to * 4);
#pragma unroll
        for (int n = 0; n < 8; ++n) {
            float4 av = *reinterpret_cast<const float4*>(&sAgg[(nb + n) * kF + k]);
#pragma unroll
            for (int j = 0; j < 4; ++j) {
                const float* w0 = reinterpret_cast<const float*>(&wt[0]);
                const float* w1 = reinterpret_cast<const float*>(&wt[1]);
                const float* w2 = reinterpret_cast<const float*>(&wt[2]);
                const float* w3 = reinterpret_cast<const float*>(&wt[3]);
                acc[n][j] += av.x * w0[j] + av.y * w1[j] + av.z * w2[j] + av.w * w3[j];
            }
        }
    }
#pragma unroll
    for (int n = 0; n < 8; ++n) {
        int node = n0 + nb + n;
        if (node < kNodes) {
            float4 r;
            r.x = 1.0f - 2.0f / (__expf(2.0f * (acc[n][0] + sB[to * 4 + 0])) + 1.0f);
            r.y = 1.0f - 2.0f / (__expf(2.0f * (acc[n][1] + sB[to * 4 + 1])) + 1.0f);
            r.z = 1.0f - 2.0f / (__expf(2.0f * (acc[n][2] + sB[to * 4 + 2])) + 1.0f);
            r.w = 1.0f - 2.0f / (__expf(2.0f * (acc[n][3] + sB[to * 4 + 3])) + 1.0f);
            *reinterpret_cast<float4*>(inout + (size_t)node * kF + to * 4) = r;
        }
    }
}

// ---------------------------------------------------------------------------
extern "C" void kernel_launch(void* const* d_in, const int* in_sizes, int n_in,
                              void* d_out, int out_size, void* d_ws, size_t ws_size,
                              hipStream_t stream) {
    const float* feature = (const float*)d_in[0];
    const float* W       = (const float*)d_in[1];
    const float* b       = (const float*)d_in[2];
    const int*   src     = (const int*)d_in[3];
    const int*   dst     = (const int*)d_in[4];
    float* out = (float*)d_out;

    char* ws = (char*)d_ws;
    _Float16* Wfrag  = (_Float16*)(ws + kOffWt);
    float*    Wt     = (float*)(ws + kOffWt);
    int*      cntA   = (int*)(ws + kOffCnt);
    unsigned int* pool = (unsigned int*)(ws + kOffPool);
    unsigned short* bucket = (unsigned short*)(ws + kOffBucket);
    int*      deg    = (int*)(ws + kOffDeg);
    uint2*    Gpk2   = (uint2*)(ws + kOffGpk);

    if (ws_size >= kWsNeeded) {   // ws_size constant across calls -> graph-safe
        prep0<<<(kF * kF + 255) / 256, 256, 0, stream>>>(W, Wfrag);
        binA<<<kABlk, 256, 0, stream>>>(src, dst, pool, cntA);
        place_gemm<<<kFusedB, 256, 0, stream>>>(
            feature, Wfrag, pool, cntA, bucket, deg, Gpk2);
        gather_tanh<<<(kNodes + 3) / 4, 256, 0, stream>>>(
            (const uint4*)Gpk2, bucket, deg, b, out);
    } else {
        prep0_fb<<<(kF * kF + 255) / 256, 256, 0, stream>>>(W, Wt);
        hipMemsetAsync(out, 0, (size_t)kNodes * kF * sizeof(float), stream);
        scatter_add<<<(kEdges * 32) / 256, 256, 0, stream>>>(feature, src, dst, out);
        linear_tanh<<<(kNodes + 63) / 64, 256, 0, stream>>>(out, Wt, b);
    }
}

// Round 9
// 134.659 us; speedup vs baseline: 1.9892x; 1.0294x over previous
//
#include <hip/hip_runtime.h>
#include <hip/hip_fp16.h>
#include <math.h>

constexpr int kNodes = 50000;
constexpr int kEdges = 600000;
constexpr int kF     = 128;
constexpr int kCap   = 48;        // bucket capacity/node; P(deg>=48) ~ 3e-15/node

// two-phase bucket build geometry (R8, verified)
constexpr int kRS      = 256;                      // nodes per range (loc = d & 255)
constexpr int kRanges  = (kNodes + kRS - 1) / kRS; // 196 (r = d >> 8)
constexpr int kABlk    = 586;                      // bin blocks, 1024 edges each
constexpr int kSegCap  = 24;                       // per-(block,range) segment cap
                                                   // lambda=5.22 -> P(any overflow) ~8e-4, graph fixed
constexpr int kI4      = kEdges / 4;               // 150000 int4s (exact)
constexpr int kPrepB   = (kF * kF) / 256;          // 64 blocks of W-pack work
constexpr int kBinTotB = kABlk + kPrepB;           // 650 (R9: prep0 merged in)

// gemm geometry (R9): half-strips — each wave covers 16 nodes x 64 outs.
// 50000/16*2 = 6250 waves = 24/CU (was 3125 = 12/CU): the R4-measured 18us
// gemm was TLP-starved (1.4 TB/s, 900cy HBM latency vs ~500cy work/wave).
constexpr int kNPB    = 32;                          // nodes per 4-wave block
constexpr int kGemmB  = (kNodes + kNPB - 1) / kNPB;  // 1563
constexpr int kFusedB = kRanges + kGemmB;            // 1759

// workspace layout (bytes)
constexpr size_t kOffWt     = 0;                                        // 32 KB Wfrag
constexpr size_t kOffCnt    = 65536;                                    // cntA[r][b] 196x586 int = 459424
constexpr size_t kOffPool   = kOffCnt + (size_t)kRanges * kABlk * 4;    // 524960 (16B-aligned)
constexpr size_t kOffBucket = kOffPool + (size_t)kABlk * kRanges * kSegCap * 4;  // 11.55 MB
constexpr size_t kOffDeg    = kOffBucket + (size_t)kNodes * kCap * 2;   // +4.8 MB
constexpr size_t kOffGpk    = kOffDeg + (size_t)kNodes * 4;             // 16B-aligned (16551136)
constexpr size_t kWsNeeded  = kOffGpk + (size_t)kNodes * kF * 2;        // ~28 MiB

typedef _Float16 f16x8 __attribute__((ext_vector_type(8)));
typedef float    f32x4 __attribute__((ext_vector_type(4)));

static __device__ __forceinline__ unsigned int packh2(float a, float b) {
    __half2 h = __floats2half2_rn(a, b);
    return *reinterpret_cast<unsigned int*>(&h);
}

// ---------------------------------------------------------------------------
// Kernel A (R9: binA + W-pack merged — one launch saved). Blocks [0,586):
// bin edges by dst-range into fixed-capacity pool segments. Block b owns
// edges [b*1024,(b+1)*1024): coalesced int4 reads, each edge read ONCE. LDS
// counters give the within-segment slot — NO global atomics. Entry =
// (loc<<16)|src. Pool layout [b][r] (contiguous 18.8KB write window); cntA
// layout [r][b] (phase-B-contiguous). Blocks [586,650): pack W into MFMA
// A-fragment order as f16: lane l, elem e -> row o=l&15, k=(l>>4)*8+e;
// linear Wf[(((nt*4)+ks)*64+l)*8+e].
__global__ __launch_bounds__(256) void binA(const int* __restrict__ src,
                                            const int* __restrict__ dst,
                                            unsigned int* __restrict__ pool,
                                            int* __restrict__ cntA,
                                            const float* __restrict__ W,
                                            _Float16* __restrict__ Wf) {
    __shared__ int c[kRanges];
    const int t = threadIdx.x;
    const int b = blockIdx.x;

    if (b >= kABlk) {
        int gid = (b - kABlk) * 256 + t;         // 0..16383
        int e  = gid & 7;
        int l  = (gid >> 3) & 63;
        int ks = (gid >> 9) & 3;
        int nt = gid >> 11;                      // 0..7
        int o  = nt * 16 + (l & 15);
        int k  = ks * 32 + ((l >> 4) & 3) * 8 + e;
        Wf[gid] = (_Float16)W[o * kF + k];
        return;
    }

    if (t < kRanges) c[t] = 0;
    __syncthreads();

    const int i4 = b * 256 + t;
    if (i4 < kI4) {
        int4 d4 = *reinterpret_cast<const int4*>(dst + i4 * 4);
        int4 s4 = *reinterpret_cast<const int4*>(src + i4 * 4);
        int dd[4] = {d4.x, d4.y, d4.z, d4.w};
        int ss[4] = {s4.x, s4.y, s4.z, s4.w};
#pragma unroll
        for (int j = 0; j < 4; ++j) {
            int r   = dd[j] >> 8;            // 0..195
            int loc = dd[j] & (kRS - 1);     // 0..255
            int p   = atomicAdd(&c[r], 1);   // LDS atomic
            if (p < kSegCap)                 // never triggers (see kSegCap note)
                pool[((size_t)b * kRanges + r) * kSegCap + p] =
                    ((unsigned)loc << 16) | (unsigned)ss[j];
        }
    }
    __syncthreads();
    if (t < kRanges) cntA[(size_t)t * kABlk + b] = min(c[t], kSegCap);
}

// prep for the vestigial fallback path: fp32 W transpose
__global__ __launch_bounds__(256) void prep0_fb(const float* __restrict__ W,
                                                float* __restrict__ Wt) {
    int gid = blockIdx.x * 256 + threadIdx.x;
    if (gid < kF * kF) {
        int k = gid >> 7;
        int o = gid & (kF - 1);
        Wt[gid] = W[o * kF + k];
    }
}

// ---------------------------------------------------------------------------
// Kernel 1: fused place + MFMA gemm.
//
// PLACE (blocks [0,196)): block r owns nodes [r*256, r*256+256). Loads its
// 586 segment counts (contiguous) into LDS, reads segments as 16B uint4
// (96B-aligned segments), places entries via LDS cursor atomics into the
// single-run ushort bucket. 100% hit rate, no global atomics. Writes deg[].
// Place blocks are latency-serial but tiny; their stalls hide under the
// co-resident gemm waves.
//
// GEMM (blocks [196,1759)): R9 half-strips. Block covers 32 nodes; wave w:
// nodes n0+(w>>1)*16, outs (w&1)*64..+64 (nt 0..3 of 8 halved). Per wave:
// all 8 F-loads upfront, W fragments double-buffered across ks,
// split-precision F (hi+lo f16, chained MFMAs). 6250 waves = 24/CU doubles
// latency hiding vs R8's 12/CU (R4 measured that variant TLP-starved at
// 1.4 TB/s). F traffic doubles to 51 MB — fine, we're latency- not
// BW-bound. No LDS use in gemm blocks.
__global__ __launch_bounds__(256, 3) void place_gemm(const float* __restrict__ F,
                                                     const _Float16* __restrict__ Wf,
                                                     const unsigned int* __restrict__ pool,
                                                     const int* __restrict__ cntA,
                                                     unsigned short* __restrict__ bucket,
                                                     int* __restrict__ deg,
                                                     uint2* __restrict__ Gpk2) {
    __shared__ int curs[kRS];
    __shared__ int scnt[kABlk];

    const int t = threadIdx.x;
    const int b = blockIdx.x;

    if (b < kRanges) {
        // ---- place phase ----
        const int r = b;
        curs[t] = 0;
        for (int i = t; i < kABlk; i += 256) scnt[i] = cntA[(size_t)r * kABlk + i];
        __syncthreads();

        for (int b2 = t; b2 < kABlk; b2 += 256) {
            const int cnt = scnt[b2];
            const unsigned int* segp = pool + ((size_t)b2 * kRanges + r) * kSegCap;
            for (int i = 0; i < cnt; i += 4) {
                uint4 u4 = *reinterpret_cast<const uint4*>(segp + i);  // 96B-aligned seg
                unsigned uu[4] = {u4.x, u4.y, u4.z, u4.w};
#pragma unroll
                for (int j = 0; j < 4; ++j) {
                    if (i + j < cnt) {
                        int loc = (int)(uu[j] >> 16);
                        int s   = (int)(uu[j] & 0xFFFFu);
                        int q   = atomicAdd(&curs[loc], 1);   // LDS atomic
                        if (q < kCap)
                            bucket[(size_t)(r * kRS + loc) * kCap + q] = (unsigned short)s;
                    }
                }
            }
        }
        __syncthreads();
        const int node = r * kRS + t;
        if (node < kNodes) deg[node] = min(curs[t], kCap);
        return;
    }

    // ---- GEMM phase (half-strip: 16 nodes x 64 outs per wave) ----
    const int tile = b - kRanges;           // 0..1562
    const int n0  = tile * kNPB;
    const int w   = t >> 6;                 // wave 0..3
    const int l   = t & 63;
    const int m0w = n0 + (w >> 1) * 16;     // node base for this wave
    if (m0w >= kNodes) return;              // tail block: high waves fully OOB
    const int ntB = (w & 1) * 4;            // out-tile base: nt ntB..ntB+3
    const int node  = m0w + (l & 15);       // B-operand col -> node
    const int nodeC = node < kNodes ? node : kNodes - 1;
    const int kbase = (l >> 4) * 8;         // this lane's K sub-chunk

    const f16x8* Wf8 = reinterpret_cast<const f16x8*>(Wf);
    const float* frow = F + (size_t)nodeC * kF + kbase;

    // 1) issue ALL F loads upfront (8 independent dwordx4)
    float4 f4[8];
#pragma unroll
    for (int ks = 0; ks < 4; ++ks) {
        f4[ks * 2 + 0] = *reinterpret_cast<const float4*>(frow + ks * 32);
        f4[ks * 2 + 1] = *reinterpret_cast<const float4*>(frow + ks * 32 + 4);
    }

    // 2) issue first W slice (ks=0) while F converts
    f16x8 wq[4];
#pragma unroll
    for (int nt = 0; nt < 4; ++nt) wq[nt] = Wf8[((ntB + nt) * 4 + 0) * 64 + l];

    // 3) split F into hi/lo f16
    f16x8 bhi[4], blo[4];
#pragma unroll
    for (int ks = 0; ks < 4; ++ks) {
        const float* fv0 = reinterpret_cast<const float*>(&f4[ks * 2]);
#pragma unroll
        for (int i = 0; i < 8; ++i) {
            float v = fv0[i];
            _Float16 h = (_Float16)v;
            bhi[ks][i] = h;
            blo[ks][i] = (_Float16)(v - (float)h);
        }
    }

    f32x4 acc[4];
#pragma unroll
    for (int nt = 0; nt < 4; ++nt) acc[nt] = (f32x4){0.f, 0.f, 0.f, 0.f};

    // 4) ks loop: MFMA current W slice while prefetching the next
#pragma unroll
    for (int ks = 0; ks < 4; ++ks) {
        f16x8 wn[4];
        if (ks < 3) {
#pragma unroll
            for (int nt = 0; nt < 4; ++nt) wn[nt] = Wf8[((ntB + nt) * 4 + ks + 1) * 64 + l];
        }
#pragma unroll
        for (int nt = 0; nt < 4; ++nt) {
            acc[nt] = __builtin_amdgcn_mfma_f32_16x16x32_f16(wq[nt], bhi[ks], acc[nt], 0, 0, 0);
            acc[nt] = __builtin_amdgcn_mfma_f32_16x16x32_f16(wq[nt], blo[ks], acc[nt], 0, 0, 0);
        }
        if (ks < 3) {
#pragma unroll
            for (int nt = 0; nt < 4; ++nt) wq[nt] = wn[nt];
        }
    }

    if (node < kNodes) {
        // acc[nt][j] = G[node][(ntB+nt)*16 + (l>>4)*4 + j]
#pragma unroll
        for (int nt = 0; nt < 4; ++nt) {
            uint2 p;
            p.x = packh2(acc[nt][0], acc[nt][1]);
            p.y = packh2(acc[nt][2], acc[nt][3]);
            Gpk2[(size_t)node * 32 + (ntB + nt) * 4 + (l >> 4)] = p;
        }
    }
}

// ---------------------------------------------------------------------------
// Kernel 2: out[n] = tanh(sum_{e: dst=n} G[src_e] + b). One wave per node,
// 4 edge-groups x 16 lanes; lane reads uint4 = 8 fp16 cols. Edge ids are
// prefetched once per wave and broadcast via __shfl. Single-run bucket,
// deg from dense deg[] array. (Verified R8.)
// CORRECTNESS NOTE: the j-loop is WAVE-UNIFORM (iters = ceil(deg/4)) so the
// ds_bpermute behind __shfl always executes with all 64 lanes active —
// bpermute from an EXEC-inactive source lane returns undefined data. Only
// the load+accumulate is predicated.
__global__ __launch_bounds__(256) void gather_tanh(const uint4* __restrict__ Gpk4,
                                                   const unsigned short* __restrict__ bucket,
                                                   const int* __restrict__ deg_arr,
                                                   const float* __restrict__ bias,
                                                   float* __restrict__ out) {
    const int wave = (blockIdx.x * 256 + threadIdx.x) >> 6;
    const int lane = threadIdx.x & 63;
    if (wave >= kNodes) return;
    const int grp = lane >> 4;      // 0..3 : edge group
    const int sub = lane & 15;      // 0..15 : cols [sub*8, sub*8+8)

    const int deg = min(deg_arr[wave], kCap);
    const size_t base = (size_t)wave * kCap;

    // one coalesced load of all edge ids for this node (deg <= 48 < 64)
    int eid = (lane < deg) ? (int)bucket[base + lane] : 0;

    float acc[8];
#pragma unroll
    for (int i = 0; i < 8; ++i) acc[i] = 0.0f;

    const int iters = (deg + 3) >> 2;   // uniform across the wave
#pragma unroll 2
    for (int i = 0; i < iters; ++i) {
        const int j = grp + 4 * i;
        const bool valid = (j < deg);
        int s = __shfl(eid, valid ? j : 0);   // full exec mask -> defined
        if (valid) {
            uint4 u = Gpk4[(size_t)s * 16 + sub];       // 16B -> 8 fp16
            const __half2* hp = reinterpret_cast<const __half2*>(&u);
#pragma unroll
            for (int q = 0; q < 4; ++q) {
                float2 f = __half22float2(hp[q]);
                acc[2 * q]     += f.x;
                acc[2 * q + 1] += f.y;
            }
        }
    }

#pragma unroll
    for (int i = 0; i < 8; ++i) {
        acc[i] += __shfl_xor(acc[i], 16);
        acc[i] += __shfl_xor(acc[i], 32);
    }

    if (grp == 0) {
        float4 b0 = *reinterpret_cast<const float4*>(bias + sub * 8);
        float4 b1 = *reinterpret_cast<const float4*>(bias + sub * 8 + 4);
        float4 r0, r1;
        r0.x = 1.0f - 2.0f / (__expf(2.0f * (acc[0] + b0.x)) + 1.0f);
        r0.y = 1.0f - 2.0f / (__expf(2.0f * (acc[1] + b0.y)) + 1.0f);
        r0.z = 1.0f - 2.0f / (__expf(2.0f * (acc[2] + b0.z)) + 1.0f);
        r0.w = 1.0f - 2.0f / (__expf(2.0f * (acc[3] + b0.w)) + 1.0f);
        r1.x = 1.0f - 2.0f / (__expf(2.0f * (acc[4] + b1.x)) + 1.0f);
        r1.y = 1.0f - 2.0f / (__expf(2.0f * (acc[5] + b1.y)) + 1.0f);
        r1.z = 1.0f - 2.0f / (__expf(2.0f * (acc[6] + b1.z)) + 1.0f);
        r1.w = 1.0f - 2.0f / (__expf(2.0f * (acc[7] + b1.w)) + 1.0f);
        float4* dstp = reinterpret_cast<float4*>(out + (size_t)wave * kF + sub * 8);
        dstp[0] = r0;
        dstp[1] = r1;
    }
}

// ---------------------------------------------------------------------------
// Fallback (vestigial — measured ws_size is 256 MiB): R1-style atomic scatter.
__global__ __launch_bounds__(256) void scatter_add(const float* __restrict__ feature,
                                                   const int* __restrict__ src,
                                                   const int* __restrict__ dst,
                                                   float* __restrict__ agg) {
    int gid = blockIdx.x * 256 + threadIdx.x;
    int e = gid >> 5;
    int c = (gid & 31) << 2;
    float4 v = *reinterpret_cast<const float4*>(feature + (size_t)src[e] * kF + c);
    float* p = agg + (size_t)dst[e] * kF + c;
    atomicAdd(p + 0, v.x);
    atomicAdd(p + 1, v.y);
    atomicAdd(p + 2, v.z);
    atomicAdd(p + 3, v.w);
}

__global__ __launch_bounds__(256, 4) void linear_tanh(float* __restrict__ inout,
                                                      const float* __restrict__ Wt,
                                                      const float* __restrict__ bias) {
    __shared__ float sAgg[64 * kF];
    __shared__ float sB[kF];
    const int t  = threadIdx.x;
    const int n0 = blockIdx.x * 64;
    if (t < kF) sB[t] = bias[t];
    const int rows = min(64, kNodes - n0);
    for (int i = t * 4; i < rows * kF; i += 256 * 4)
        *reinterpret_cast<float4*>(&sAgg[i]) =
            *reinterpret_cast<const float4*>(inout + (size_t)n0 * kF + i);
    __syncthreads();
    const int tn = t >> 5, to = t & 31, nb = tn * 8;
    float acc[8][4];
#pragma unroll
    for (int n = 0; n < 8; ++n)
#pragma unroll
        for (int j = 0; j < 4; ++j) acc[n][j] = 0.0f;
    for (int k = 0; k < kF; k += 4) {
        float4 wt[4];
#pragma unroll
        for (int i = 0; i < 4; ++i)
            wt[i] = *reinterpret_cast<const float4*>(Wt + (k + i) * kF + to * 4);
#pragma unroll
        for (int n = 0; n < 8; ++n) {
            float4 av = *reinterpret_cast<const float4*>(&sAgg[(nb + n) * kF + k]);
#pragma unroll
            for (int j = 0; j < 4; ++j) {
                const float* w0 = reinterpret_cast<const float*>(&wt[0]);
                const float* w1 = reinterpret_cast<const float*>(&wt[1]);
                const float* w2 = reinterpret_cast<const float*>(&wt[2]);
                const float* w3 = reinterpret_cast<const float*>(&wt[3]);
                acc[n][j] += av.x * w0[j] + av.y * w1[j] + av.z * w2[j] + av.w * w3[j];
            }
        }
    }
#pragma unroll
    for (int n = 0; n < 8; ++n) {
        int node = n0 + nb + n;
        if (node < kNodes) {
            float4 r;
            r.x = 1.0f - 2.0f / (__expf(2.0f * (acc[n][0] + sB[to * 4 + 0])) + 1.0f);
            r.y = 1.0f - 2.0f / (__expf(2.0f * (acc[n][1] + sB[to * 4 + 1])) + 1.0f);
            r.z = 1.0f - 2.0f / (__expf(2.0f * (acc[n][2] + sB[to * 4 + 2])) + 1.0f);
            r.w = 1.0f - 2.0f / (__expf(2.0f * (acc[n][3] + sB[to * 4 + 3])) + 1.0f);
            *reinterpret_cast<float4*>(inout + (size_t)node * kF + to * 4) = r;
        }
    }
}

// ---------------------------------------------------------------------------
extern "C" void kernel_launch(void* const* d_in, const int* in_sizes, int n_in,
                              void* d_out, int out_size, void* d_ws, size_t ws_size,
                              hipStream_t stream) {
    const float* feature = (const float*)d_in[0];
    const float* W       = (const float*)d_in[1];
    const float* b       = (const float*)d_in[2];
    const int*   src     = (const int*)d_in[3];
    const int*   dst     = (const int*)d_in[4];
    float* out = (float*)d_out;

    char* ws = (char*)d_ws;
    _Float16* Wfrag  = (_Float16*)(ws + kOffWt);
    float*    Wt     = (float*)(ws + kOffWt);
    int*      cntA   = (int*)(ws + kOffCnt);
    unsigned int* pool = (unsigned int*)(ws + kOffPool);
    unsigned short* bucket = (unsigned short*)(ws + kOffBucket);
    int*      deg    = (int*)(ws + kOffDeg);
    uint2*    Gpk2   = (uint2*)(ws + kOffGpk);

    if (ws_size >= kWsNeeded) {   // ws_size constant across calls -> graph-safe
        binA<<<kBinTotB, 256, 0, stream>>>(src, dst, pool, cntA, W, Wfrag);
        place_gemm<<<kFusedB, 256, 0, stream>>>(
            feature, Wfrag, pool, cntA, bucket, deg, Gpk2);
        gather_tanh<<<(kNodes + 3) / 4, 256, 0, stream>>>(
            (const uint4*)Gpk2, bucket, deg, b, out);
    } else {
        prep0_fb<<<(kF * kF + 255) / 256, 256, 0, stream>>>(W, Wt);
        hipMemsetAsync(out, 0, (size_t)kNodes * kF * sizeof(float), stream);
        scatter_add<<<(kEdges * 32) / 256, 256, 0, stream>>>(feature, src, dst, out);
        linear_tanh<<<(kNodes + 63) / 64, 256, 0, stream>>>(out, Wt, b);
    }
}